// Round 5
// baseline (300.915 us; speedup 1.0000x reference)
//
#include <hip/hip_runtime.h>
#include <math.h>

#define D 4096
#define K 128
#define KP 129          // K+1 (augmented sqrt(EPS)*ones column)
#define NC 144          // padded col count for VbT / Yb (9 tiles of 16; cols >= 129 zero)
#define NROWS 8192
#define QS 144          // Q row stride
#define MS 132          // M row stride
#define NP 132          // padded order for k_final
#define NB 12           // k_final panel width (11 panels)
#define LOG2PI 1.8378770664093453

typedef __attribute__((ext_vector_type(8))) short bh8;     // 8 bf16 (4 VGPRs)
typedef __attribute__((ext_vector_type(4))) float f32x4;   // MFMA acc

// ---------------- helpers ----------------
__device__ __forceinline__ unsigned short f2bf(float f) {  // RNE
  unsigned int u = __float_as_uint(f);
  unsigned int r = u + 0x7FFFu + ((u >> 16) & 1u);
  return (unsigned short)(r >> 16);
}
__device__ __forceinline__ float bf2f(unsigned short u) {
  return __uint_as_float(((unsigned int)u) << 16);
}
__device__ __forceinline__ float blo(unsigned int v) { return __uint_as_float(v << 16); }
__device__ __forceinline__ float bhi(unsigned int v) { return __uint_as_float(v & 0xFFFF0000u); }

__device__ __forceinline__ float blockReduceSum256(float v) {
  #pragma unroll
  for (int off = 32; off > 0; off >>= 1) v += __shfl_down(v, off, 64);
  __shared__ float tmp[4];
  __syncthreads();
  if ((threadIdx.x & 63) == 0) tmp[threadIdx.x >> 6] = v;
  __syncthreads();
  float r = 0.0f;
  if (threadIdx.x == 0) r = tmp[0] + tmp[1] + tmp[2] + tmp[3];
  return r;                              // valid on tid 0 only
}

// ---------------- VbT[c][d] = bf16( U[d][c] / sigma[d] ), rows c>=129 zero ----------------
__global__ __launch_bounds__(256) void k_prep(const float* __restrict__ theta,
                                              unsigned short* __restrict__ VbT) {
  int c = blockIdx.x;                    // 0..143
  const float* sg = theta + (size_t)D * K + D;
  float al = (c < K) ? theta[(size_t)D * K + 2 * D + c] : 0.0f;
  for (int d = threadIdx.x; d < D; d += 256) {
    float v;
    if (c < K)       v = theta[(size_t)d * K + c] * al / sg[d];
    else if (c == K) v = 1.0e-3f / sg[d];
    else             v = 0.0f;
    VbT[(size_t)c * D + d] = f2bf(v);
  }
}

// ---------------- column stats of x (fp32 exact) ----------------
__global__ __launch_bounds__(256) void k_colstats(const float* __restrict__ x,
                                                  float* __restrict__ colsum,
                                                  float* __restrict__ colsumsq) {
  int d4 = blockIdx.x * 256 + threadIdx.x;       // float4 column index
  int i0 = blockIdx.y * 64;
  float4 s1 = {0, 0, 0, 0}, s2 = {0, 0, 0, 0};
  for (int i = i0; i < i0 + 64; ++i) {
    float4 v = *reinterpret_cast<const float4*>(&x[(size_t)i * D + d4 * 4]);
    s1.x += v.x; s1.y += v.y; s1.z += v.z; s1.w += v.w;
    s2.x += v.x * v.x; s2.y += v.y * v.y; s2.z += v.z * v.z; s2.w += v.w * v.w;
  }
  atomicAdd(&colsum[d4 * 4 + 0], s1.x); atomicAdd(&colsum[d4 * 4 + 1], s1.y);
  atomicAdd(&colsum[d4 * 4 + 2], s1.z); atomicAdd(&colsum[d4 * 4 + 3], s1.w);
  atomicAdd(&colsumsq[d4 * 4 + 0], s2.x); atomicAdd(&colsumsq[d4 * 4 + 1], s2.y);
  atomicAdd(&colsumsq[d4 * 4 + 2], s2.z); atomicAdd(&colsumsq[d4 * 4 + 3], s2.w);
}

// ---------------- M = I + sum_d sigma_d VbT[j][d] VbT[k][d] ----------------
__global__ __launch_bounds__(256) void k_M(const float* __restrict__ theta,
                                           const unsigned short* __restrict__ VbT,
                                           float* __restrict__ M) {
  int j = blockIdx.x, kk2 = blockIdx.y;
  if (kk2 < j) return;                   // symmetry
  const float* sg = theta + (size_t)D * K + D;
  float acc = 0.0f;
  for (int d0 = threadIdx.x * 8; d0 < D; d0 += 2048) {
    uint4 ua = *reinterpret_cast<const uint4*>(&VbT[(size_t)j * D + d0]);
    uint4 ub = *reinterpret_cast<const uint4*>(&VbT[(size_t)kk2 * D + d0]);
    float4 s0 = *reinterpret_cast<const float4*>(&sg[d0]);
    float4 s1 = *reinterpret_cast<const float4*>(&sg[d0 + 4]);
    acc += s0.x * blo(ua.x) * blo(ub.x) + s0.y * bhi(ua.x) * bhi(ub.x)
         + s0.z * blo(ua.y) * blo(ub.y) + s0.w * bhi(ua.y) * bhi(ub.y)
         + s1.x * blo(ua.z) * blo(ub.z) + s1.y * bhi(ua.z) * bhi(ub.z)
         + s1.z * blo(ua.w) * blo(ub.w) + s1.w * bhi(ua.w) * bhi(ub.w);
  }
  float r = blockReduceSum256(acc);
  if (threadIdx.x == 0) {
    float m = r + (j == kk2 ? 1.0f : 0.0f);
    M[j * MS + kk2] = m;
    M[kk2 * MS + j] = m;
  }
}

// ---------------- fused: tvec (b<KP), mvec (KP<=b<2KP), scalars (b==2KP) ----------------
__global__ __launch_bounds__(256) void k_small(const float* __restrict__ theta,
                                               const unsigned short* __restrict__ VbT,
                                               const float* __restrict__ colsum,
                                               const float* __restrict__ colsumsq,
                                               float* __restrict__ tvec,
                                               float* __restrict__ mvec,
                                               float* __restrict__ scalars) {
  int b = blockIdx.x;
  if (b < 2 * KP) {
    int c = (b >= KP) ? b - KP : b;
    const float* src = (b >= KP) ? (theta + (size_t)D * K) : colsum;
    float a = 0.0f;
    for (int d = threadIdx.x; d < D; d += 256) a += bf2f(VbT[(size_t)c * D + d]) * src[d];
    float r = blockReduceSum256(a);
    if (threadIdx.x == 0) { if (b < KP) tvec[c] = r; else mvec[c] = r; }
  } else {
    const float* mu = theta + (size_t)D * K;
    const float* sg = theta + (size_t)D * K + D;
    float a = 0.0f, bb = 0.0f;
    for (int d = threadIdx.x; d < D; d += 256) {
      float s = sg[d];
      float m = mu[d];
      a += logf(s);
      bb += (colsumsq[d] - 2.0f * m * colsum[d] + (float)NROWS * m * m) / s;
    }
    float ra = blockReduceSum256(a);
    float rb = blockReduceSum256(bb);
    if (threadIdx.x == 0) { scalars[0] = ra; scalars[1] = rb; }
  }
}

// ---------------- Yb = bf16( X * V )  via MFMA 16x16x32 ----------------
#define GBM 32
#define GBK 128
#define NSTEP (D / GBK)     // 32
#define XSS 136             // LDS row stride in shorts

__global__ __launch_bounds__(512) void k_gemm(const float* __restrict__ x,
                                              const unsigned short* __restrict__ VbT,
                                              unsigned short* __restrict__ Yb) {
  __shared__ unsigned short Xs[GBM][XSS];   // bf16 X tile
  __shared__ unsigned short Vs[NC][XSS];    // bf16 V^T tile
  int tid = threadIdx.x;
  int row0 = blockIdx.x * GBM;
  int wid = tid >> 6, lane = tid & 63;
  int lr = lane & 15, lk = (lane >> 4) * 8;
  int rt = wid & 1;                         // row tile (16 rows)
  int cg = wid >> 1;                        // col group
  int ct0 = (cg == 0) ? 0 : (cg * 2 + 1);   // col tiles: {0,1,2},{3,4},{5,6},{7,8}
  int nct = (cg == 0) ? 3 : 2;

  int sxr = tid >> 4;                       // X: row 0..31
  int sxk = (tid & 15) * 8;                 // X: k-octet
  int vrb = tid >> 4;                       // V: base row (+32 per j)
  int vk  = (tid & 15) * 8;

  float4 xr0, xr1;
  uint4 vr0, vr1, vr2, vr3, vr4;

  {
    const float* xb = &x[(size_t)(row0 + sxr) * D + sxk];
    xr0 = *reinterpret_cast<const float4*>(xb);
    xr1 = *reinterpret_cast<const float4*>(xb + 4);
    const unsigned short* vb = &VbT[(size_t)vrb * D + vk];
    vr0 = *reinterpret_cast<const uint4*>(vb);
    vr1 = *reinterpret_cast<const uint4*>(vb + (size_t)32 * D);
    vr2 = *reinterpret_cast<const uint4*>(vb + (size_t)64 * D);
    vr3 = *reinterpret_cast<const uint4*>(vb + (size_t)96 * D);
    if (tid < 256) vr4 = *reinterpret_cast<const uint4*>(vb + (size_t)128 * D);
  }

  f32x4 acc0 = {0, 0, 0, 0}, acc1 = {0, 0, 0, 0}, acc2 = {0, 0, 0, 0};

  for (int s = 0; s < NSTEP; ++s) {
    {
      uint4 w;
      w.x = (unsigned)f2bf(xr0.x) | ((unsigned)f2bf(xr0.y) << 16);
      w.y = (unsigned)f2bf(xr0.z) | ((unsigned)f2bf(xr0.w) << 16);
      w.z = (unsigned)f2bf(xr1.x) | ((unsigned)f2bf(xr1.y) << 16);
      w.w = (unsigned)f2bf(xr1.z) | ((unsigned)f2bf(xr1.w) << 16);
      *reinterpret_cast<uint4*>(&Xs[sxr][sxk]) = w;
      unsigned short* vd = &Vs[vrb][vk];
      *reinterpret_cast<uint4*>(vd) = vr0;
      *reinterpret_cast<uint4*>(vd + 32 * XSS) = vr1;
      *reinterpret_cast<uint4*>(vd + 64 * XSS) = vr2;
      *reinterpret_cast<uint4*>(vd + 96 * XSS) = vr3;
      if (tid < 256) *reinterpret_cast<uint4*>(vd + 128 * XSS) = vr4;
    }
    __syncthreads();
    if (s + 1 < NSTEP) {
      const float* xb = &x[(size_t)(row0 + sxr) * D + (s + 1) * GBK + sxk];
      xr0 = *reinterpret_cast<const float4*>(xb);
      xr1 = *reinterpret_cast<const float4*>(xb + 4);
      const unsigned short* vb = &VbT[(size_t)vrb * D + (s + 1) * GBK + vk];
      vr0 = *reinterpret_cast<const uint4*>(vb);
      vr1 = *reinterpret_cast<const uint4*>(vb + (size_t)32 * D);
      vr2 = *reinterpret_cast<const uint4*>(vb + (size_t)64 * D);
      vr3 = *reinterpret_cast<const uint4*>(vb + (size_t)96 * D);
      if (tid < 256) vr4 = *reinterpret_cast<const uint4*>(vb + (size_t)128 * D);
    }
    #pragma unroll
    for (int ks = 0; ks < 4; ++ks) {
      bh8 a = *reinterpret_cast<const bh8*>(&Xs[rt * 16 + lr][ks * 32 + lk]);
      bh8 b0 = *reinterpret_cast<const bh8*>(&Vs[ct0 * 16 + lr][ks * 32 + lk]);
      acc0 = __builtin_amdgcn_mfma_f32_16x16x32_bf16(a, b0, acc0, 0, 0, 0);
      bh8 b1 = *reinterpret_cast<const bh8*>(&Vs[(ct0 + 1) * 16 + lr][ks * 32 + lk]);
      acc1 = __builtin_amdgcn_mfma_f32_16x16x32_bf16(a, b1, acc1, 0, 0, 0);
      if (nct == 3) {
        bh8 b2 = *reinterpret_cast<const bh8*>(&Vs[(ct0 + 2) * 16 + lr][ks * 32 + lk]);
        acc2 = __builtin_amdgcn_mfma_f32_16x16x32_bf16(a, b2, acc2, 0, 0, 0);
      }
    }
    __syncthreads();
  }

  int rw = row0 + rt * 16 + ((lane >> 4) << 2);
  #pragma unroll
  for (int g = 0; g < 4; ++g)
    Yb[(size_t)(rw + g) * NC + ct0 * 16 + lr] = f2bf(acc0[g]);
  #pragma unroll
  for (int g = 0; g < 4; ++g)
    Yb[(size_t)(rw + g) * NC + (ct0 + 1) * 16 + lr] = f2bf(acc1[g]);
  if (nct == 3) {
    #pragma unroll
    for (int g = 0; g < 4; ++g)
      Yb[(size_t)(rw + g) * NC + (ct0 + 2) * 16 + lr] = f2bf(acc2[g]);
  }
}

// ---------------- Q += Yb^T Yb  (bf16 in, symmetry, row-split atomics) ----------------
#define SYRK_ZSPLIT 4
__global__ __launch_bounds__(256) void k_syrk(const unsigned short* __restrict__ Yb,
                                              float* __restrict__ Q) {
  int bj = blockIdx.x * 16, bk = blockIdx.y * 16;
  if (bk < bj) return;                   // symmetry
  __shared__ float Ya[64][17];
  __shared__ float Yc[64][17];
  int i0base = blockIdx.z * (NROWS / SYRK_ZSPLIT);
  int tid = threadIdx.x;
  int tj = tid & 15, tk = tid >> 4;
  int lr = tid >> 2, lc = (tid & 3) * 4;
  float acc = 0.0f;
  for (int i0 = i0base; i0 < i0base + NROWS / SYRK_ZSPLIT; i0 += 64) {
    ushort4 va = *reinterpret_cast<const ushort4*>(&Yb[(size_t)(i0 + lr) * NC + bj + lc]);
    ushort4 vc = *reinterpret_cast<const ushort4*>(&Yb[(size_t)(i0 + lr) * NC + bk + lc]);
    Ya[lr][lc + 0] = bf2f(va.x); Ya[lr][lc + 1] = bf2f(va.y);
    Ya[lr][lc + 2] = bf2f(va.z); Ya[lr][lc + 3] = bf2f(va.w);
    Yc[lr][lc + 0] = bf2f(vc.x); Yc[lr][lc + 1] = bf2f(vc.y);
    Yc[lr][lc + 2] = bf2f(vc.z); Yc[lr][lc + 3] = bf2f(vc.w);
    __syncthreads();
    #pragma unroll
    for (int ii = 0; ii < 64; ++ii) acc += Ya[ii][tj] * Yc[ii][tk];
    __syncthreads();
  }
  atomicAdd(&Q[(bj + tj) * QS + bk + tk], acc);
  if (bj != bk) atomicAdd(&Q[(bk + tk) * QS + bj + tj], acc);
}

// ---------------- final: blocked Cholesky (+diag inverses) + GEMV solves + trace ----------------
__global__ __launch_bounds__(512) void k_final(const float* __restrict__ Mg,
                                               const float* __restrict__ Qg,
                                               const float* __restrict__ tvec,
                                               const float* __restrict__ mvec,
                                               const float* __restrict__ scalars,
                                               const int* __restrict__ fds,
                                               float* __restrict__ out) {
  __shared__ float A[NP][NP];            // M (identity-padded) -> L (lower)
  __shared__ float Wm[NP][NP];           // S -> M^-1 S
  __shared__ float Gall[NP / NB][NB][NB];// per-panel L_jj^{-1}
  __shared__ float tl[NP], ml[NP];
  __shared__ float redA[8], redB[8];
  int tid = threadIdx.x;

  if (tid < NP) {
    tl[tid] = (tid < KP) ? tvec[tid] : 0.0f;
    ml[tid] = (tid < KP) ? mvec[tid] : 0.0f;
  }
  for (int idx = tid; idx < NP * NP; idx += 512) {
    int r = idx / NP, c = idx - r * NP;
    A[r][c] = (r < KP && c < KP) ? Mg[r * MS + c] : (r == c ? 1.0f : 0.0f);
  }
  __syncthreads();
  for (int idx = tid; idx < NP * NP; idx += 512) {
    int r = idx / NP, c = idx - r * NP;
    float s = 0.0f;
    if (r < KP && c < KP)
      s = Qg[r * QS + c] - tl[r] * ml[c] - ml[r] * tl[c] + (float)NROWS * ml[r] * ml[c];
    Wm[r][c] = s;
  }
  float logsum = 0.0f;
  __syncthreads();

  // ======== blocked Cholesky, with per-panel 12x12 inverse in wave-0 registers ========
  for (int p = 0; p < NP / NB; ++p) {
    int j0 = p * NB, j1 = j0 + NB;
    if (tid < 64) {
      int r = tid;
      int rr = (r < NB) ? r : 0;
      const float* arow = &A[j0 + rr][j0];
      float4 q0 = *reinterpret_cast<const float4*>(arow);
      float4 q1 = *reinterpret_cast<const float4*>(arow + 4);
      float4 q2 = *reinterpret_cast<const float4*>(arow + 8);
      float row[NB] = {q0.x, q0.y, q0.z, q0.w, q1.x, q1.y, q1.z, q1.w,
                       q2.x, q2.y, q2.z, q2.w};
      float mydiag = 1.0f;
      #pragma unroll
      for (int jj = 0; jj < NB; ++jj) {
        float s = sqrtf(__shfl(row[jj], jj));
        if (r == jj) { logsum += 2.0f * logf(s); mydiag = s; row[jj] = s; }
        else if (r > jj) row[jj] /= s;
        #pragma unroll
        for (int cc = jj + 1; cc < NB; ++cc) {
          float lc = __shfl(row[jj], cc);
          if (r > jj) row[cc] -= row[jj] * lc;
        }
      }
      if (r < NB) {
        float* wrow = &A[j0 + r][j0];
        #pragma unroll
        for (int k = 0; k < NB; ++k) if (k <= r) wrow[k] = row[k];
      }
      // in-wave inversion: G = L_jj^{-1}; column c forward substitution, ILP across c
      float myinv = 1.0f / mydiag;
      float gc[NB];
      #pragma unroll
      for (int c = 0; c < NB; ++c) {
        float t = (r == c) ? 1.0f : 0.0f;
        float cap = 0.0f;
        #pragma unroll
        for (int k2 = c; k2 < NB; ++k2) {
          float gk = __shfl(t * myinv, k2);   // lane k2 finalizes G[k2][c]
          if (r == k2) cap = gk;
          else if (r > k2) t -= row[k2] * gk;
        }
        gc[c] = cap;
      }
      if (r < NB) {
        #pragma unroll
        for (int c = 0; c < NB; ++c) Gall[p][r][c] = (c <= r) ? gc[c] : 0.0f;
      }
    }
    __syncthreads();
    // panel solve rows j1..NP: row_new = row_old * G^T   (independent FMAs)
    int nbrows = NP - j1;
    if (tid < nbrows) {
      int r = j1 + tid;
      float* arow = &A[r][j0];
      float4 q0 = *reinterpret_cast<const float4*>(arow);
      float4 q1 = *reinterpret_cast<const float4*>(arow + 4);
      float4 q2 = *reinterpret_cast<const float4*>(arow + 8);
      float ro[NB] = {q0.x, q0.y, q0.z, q0.w, q1.x, q1.y, q1.z, q1.w,
                      q2.x, q2.y, q2.z, q2.w};
      float rn[NB];
      #pragma unroll
      for (int cc = 0; cc < NB; ++cc) {
        float s = 0.0f;
        #pragma unroll
        for (int k = 0; k <= cc; ++k) s += ro[k] * Gall[p][cc][k];
        rn[cc] = s;
      }
      float4 w0 = {rn[0], rn[1], rn[2], rn[3]};
      float4 w1 = {rn[4], rn[5], rn[6], rn[7]};
      float4 w2 = {rn[8], rn[9], rn[10], rn[11]};
      *reinterpret_cast<float4*>(arow) = w0;
      *reinterpret_cast<float4*>(arow + 4) = w1;
      *reinterpret_cast<float4*>(arow + 8) = w2;
    }
    __syncthreads();
    // trailing rank-12 update, lower blocks only, 4x4 tasks
    int nt4 = nbrows / 4;
    for (int t = tid; t < nt4 * nt4; t += 512) {
      int r4 = t / nt4, c4 = t - r4 * nt4;
      if (c4 > r4) continue;
      int r = j1 + r4 * 4, c = j1 + c4 * 4;
      float4 a0 = *reinterpret_cast<float4*>(&A[r + 0][c]);
      float4 a1 = *reinterpret_cast<float4*>(&A[r + 1][c]);
      float4 a2 = *reinterpret_cast<float4*>(&A[r + 2][c]);
      float4 a3 = *reinterpret_cast<float4*>(&A[r + 3][c]);
      #pragma unroll
      for (int k = 0; k < NB; ++k) {
        float pc0 = A[c + 0][j0 + k], pc1 = A[c + 1][j0 + k];
        float pc2 = A[c + 2][j0 + k], pc3 = A[c + 3][j0 + k];
        float pr0 = A[r + 0][j0 + k], pr1 = A[r + 1][j0 + k];
        float pr2 = A[r + 2][j0 + k], pr3 = A[r + 3][j0 + k];
        a0.x -= pr0 * pc0; a0.y -= pr0 * pc1; a0.z -= pr0 * pc2; a0.w -= pr0 * pc3;
        a1.x -= pr1 * pc0; a1.y -= pr1 * pc1; a1.z -= pr1 * pc2; a1.w -= pr1 * pc3;
        a2.x -= pr2 * pc0; a2.y -= pr2 * pc1; a2.z -= pr2 * pc2; a2.w -= pr2 * pc3;
        a3.x -= pr3 * pc0; a3.y -= pr3 * pc1; a3.z -= pr3 * pc2; a3.w -= pr3 * pc3;
      }
      *reinterpret_cast<float4*>(&A[r + 0][c]) = a0;
      *reinterpret_cast<float4*>(&A[r + 1][c]) = a1;
      *reinterpret_cast<float4*>(&A[r + 2][c]) = a2;
      *reinterpret_cast<float4*>(&A[r + 3][c]) = a3;
    }
    __syncthreads();
  }

  // ======== forward solve: L W = S  (diag step = GEMV with G) ========
  for (int p = 0; p < NP / NB; ++p) {
    int j0 = p * NB, j1 = j0 + NB;
    if (tid < NP) {
      int c = tid;
      float w[NB], wn[NB];
      #pragma unroll
      for (int k = 0; k < NB; ++k) w[k] = Wm[j0 + k][c];
      #pragma unroll
      for (int kk = 0; kk < NB; ++kk) {
        float s = 0.0f;
        #pragma unroll
        for (int k = 0; k <= kk; ++k) s += Gall[p][kk][k] * w[k];
        wn[kk] = s;
      }
      #pragma unroll
      for (int k = 0; k < NB; ++k) Wm[j0 + k][c] = wn[k];
    }
    __syncthreads();
    int nbrows = NP - j1;
    int nr4 = nbrows / 4, nc4 = NP / 4;
    for (int t = tid; t < nr4 * nc4; t += 512) {
      int r4 = t / nc4, c4 = t - r4 * nc4;
      int r = j1 + r4 * 4, c = c4 * 4;
      float4 a0 = *reinterpret_cast<float4*>(&Wm[r + 0][c]);
      float4 a1 = *reinterpret_cast<float4*>(&Wm[r + 1][c]);
      float4 a2 = *reinterpret_cast<float4*>(&Wm[r + 2][c]);
      float4 a3 = *reinterpret_cast<float4*>(&Wm[r + 3][c]);
      #pragma unroll
      for (int k = 0; k < NB; ++k) {
        float l0 = A[r + 0][j0 + k], l1 = A[r + 1][j0 + k];
        float l2 = A[r + 2][j0 + k], l3 = A[r + 3][j0 + k];
        float4 wr = *reinterpret_cast<const float4*>(&Wm[j0 + k][c]);
        a0.x -= l0 * wr.x; a0.y -= l0 * wr.y; a0.z -= l0 * wr.z; a0.w -= l0 * wr.w;
        a1.x -= l1 * wr.x; a1.y -= l1 * wr.y; a1.z -= l1 * wr.z; a1.w -= l1 * wr.w;
        a2.x -= l2 * wr.x; a2.y -= l2 * wr.y; a2.z -= l2 * wr.z; a2.w -= l2 * wr.w;
        a3.x -= l3 * wr.x; a3.y -= l3 * wr.y; a3.z -= l3 * wr.z; a3.w -= l3 * wr.w;
      }
      *reinterpret_cast<float4*>(&Wm[r + 0][c]) = a0;
      *reinterpret_cast<float4*>(&Wm[r + 1][c]) = a1;
      *reinterpret_cast<float4*>(&Wm[r + 2][c]) = a2;
      *reinterpret_cast<float4*>(&Wm[r + 3][c]) = a3;
    }
    __syncthreads();
  }

  // ======== backward solve: L^T U = W  (diag step = GEMV with G^T) ========
  for (int p = NP / NB - 1; p >= 0; --p) {
    int j0 = p * NB;
    if (tid < NP) {
      int c = tid;
      float w[NB], wn[NB];
      #pragma unroll
      for (int k = 0; k < NB; ++k) w[k] = Wm[j0 + k][c];
      #pragma unroll
      for (int kk = 0; kk < NB; ++kk) {
        float s = 0.0f;
        #pragma unroll
        for (int k = kk; k < NB; ++k) s += Gall[p][k][kk] * w[k];
        wn[kk] = s;
      }
      #pragma unroll
      for (int k = 0; k < NB; ++k) Wm[j0 + k][c] = wn[k];
    }
    __syncthreads();
    int nr4 = j0 / 4, nc4 = NP / 4;
    for (int t = tid; t < nr4 * nc4; t += 512) {
      int r4 = t / nc4, c4 = t - r4 * nc4;
      int r = r4 * 4, c = c4 * 4;
      float4 a0 = *reinterpret_cast<float4*>(&Wm[r + 0][c]);
      float4 a1 = *reinterpret_cast<float4*>(&Wm[r + 1][c]);
      float4 a2 = *reinterpret_cast<float4*>(&Wm[r + 2][c]);
      float4 a3 = *reinterpret_cast<float4*>(&Wm[r + 3][c]);
      #pragma unroll
      for (int k = 0; k < NB; ++k) {
        float l0 = A[j0 + k][r + 0], l1 = A[j0 + k][r + 1];
        float l2 = A[j0 + k][r + 2], l3 = A[j0 + k][r + 3];
        float4 wr = *reinterpret_cast<const float4*>(&Wm[j0 + k][c]);
        a0.x -= l0 * wr.x; a0.y -= l0 * wr.y; a0.z -= l0 * wr.z; a0.w -= l0 * wr.w;
        a1.x -= l1 * wr.x; a1.y -= l1 * wr.y; a1.z -= l1 * wr.z; a1.w -= l1 * wr.w;
        a2.x -= l2 * wr.x; a2.y -= l2 * wr.y; a2.z -= l2 * wr.z; a2.w -= l2 * wr.w;
        a3.x -= l3 * wr.x; a3.y -= l3 * wr.y; a3.z -= l3 * wr.z; a3.w -= l3 * wr.w;
      }
      *reinterpret_cast<float4*>(&Wm[r + 0][c]) = a0;
      *reinterpret_cast<float4*>(&Wm[r + 1][c]) = a1;
      *reinterpret_cast<float4*>(&Wm[r + 2][c]) = a2;
      *reinterpret_cast<float4*>(&Wm[r + 3][c]) = a3;
    }
    __syncthreads();
  }

  // ======== trace + logdet + combine ========
  float dv = (tid < KP) ? Wm[tid][tid] : 0.0f;
  float v1 = dv, v2 = logsum;
  #pragma unroll
  for (int off = 32; off > 0; off >>= 1) {
    v1 += __shfl_down(v1, off, 64);
    v2 += __shfl_down(v2, off, 64);
  }
  if ((tid & 63) == 0) { redA[tid >> 6] = v1; redB[tid >> 6] = v2; }
  __syncthreads();
  if (tid == 0) {
    float tr = 0.0f, logdetM = 0.0f;
    #pragma unroll
    for (int i = 0; i < 8; ++i) { tr += redA[i]; logdetM += redB[i]; }
    double sumlog = (double)scalars[0];
    double term1  = (double)scalars[1];
    double total = (double)NROWS * (double)D * LOG2PI
                 + (double)NROWS * (sumlog + (double)logdetM)
                 + term1 - (double)tr;
    double scale = (double)fds[0] / (double)NROWS;
    out[0] = (float)(scale * (-0.5) * total);
  }
}

// ---------------- launch ----------------
extern "C" void kernel_launch(void* const* d_in, const int* in_sizes, int n_in,
                              void* d_out, int out_size, void* d_ws, size_t ws_size,
                              hipStream_t stream) {
  const float* x     = (const float*)d_in[0];
  const float* theta = (const float*)d_in[1];
  const int*   fds   = (const int*)d_in[2];
  float* out = (float*)d_out;
  char* ws = (char*)d_ws;

  unsigned short* Yb  = (unsigned short*)ws;                       // 8192*144*2 = 2359296
  unsigned short* VbT = (unsigned short*)(ws + 2359296);           // 144*4096*2 = 1179648
  float* Q        = (float*)(ws + 2359296 + 1179648);              // QS*QS*4 = 82944
  float* colsum   = (float*)(ws + 2359296 + 1179648 + 82944);      // D*4
  float* colsumsq = colsum + D;                                    // D*4
  float* M        = colsumsq + D;                                  // KP*MS*4
  float* tvec     = M + KP * MS;
  float* mvec     = tvec + MS;
  float* scalars  = mvec + MS;

  // zero atomic accumulators: Q + colsum + colsumsq (contiguous)
  hipMemsetAsync(Q, 0, (size_t)(QS * QS + 2 * D) * sizeof(float), stream);

  k_colstats <<<dim3(D / 4 / 256, 128), 256, 0, stream>>>(x, colsum, colsumsq);
  k_prep     <<<dim3(NC), 256, 0, stream>>>(theta, VbT);
  k_gemm     <<<dim3(NROWS / GBM), 512, 0, stream>>>(x, VbT, Yb);
  k_M        <<<dim3(KP, KP), 256, 0, stream>>>(theta, VbT, M);
  k_small    <<<dim3(2 * KP + 1), 256, 0, stream>>>(theta, VbT, colsum, colsumsq,
                                                    tvec, mvec, scalars);
  k_syrk     <<<dim3(QS / 16, QS / 16, SYRK_ZSPLIT), 256, 0, stream>>>(Yb, Q);
  k_final    <<<dim3(1), 512, 0, stream>>>(M, Q, tvec, mvec, scalars, fds, out);
}

// Round 6
// 276.430 us; speedup vs baseline: 1.0886x; 1.0886x over previous
//
#include <hip/hip_runtime.h>
#include <math.h>

#define D 4096
#define K 128
#define KP 129          // K+1 (augmented sqrt(EPS)*ones column)
#define NC 144          // padded col count for VbT / Yb (9 tiles of 16; cols >= 129 zero)
#define NROWS 8192
#define QS 144          // Q row stride
#define MS 132          // M row stride
#define NP 132          // padded order for k_final
#define NB 12           // k_final panel width (11 panels)
#define NPAN (NP / NB)
#define LOG2PI 1.8378770664093453

typedef __attribute__((ext_vector_type(8))) short bh8;     // 8 bf16 (4 VGPRs)
typedef __attribute__((ext_vector_type(4))) float f32x4;   // MFMA acc

// ---------------- helpers ----------------
__device__ __forceinline__ unsigned short f2bf(float f) {  // RNE
  unsigned int u = __float_as_uint(f);
  unsigned int r = u + 0x7FFFu + ((u >> 16) & 1u);
  return (unsigned short)(r >> 16);
}
__device__ __forceinline__ float bf2f(unsigned short u) {
  return __uint_as_float(((unsigned int)u) << 16);
}
__device__ __forceinline__ float blo(unsigned int v) { return __uint_as_float(v << 16); }
__device__ __forceinline__ float bhi(unsigned int v) { return __uint_as_float(v & 0xFFFF0000u); }

__device__ __forceinline__ float blockReduceSum256(float v) {
  #pragma unroll
  for (int off = 32; off > 0; off >>= 1) v += __shfl_down(v, off, 64);
  __shared__ float tmp[4];
  __syncthreads();
  if ((threadIdx.x & 63) == 0) tmp[threadIdx.x >> 6] = v;
  __syncthreads();
  float r = 0.0f;
  if (threadIdx.x == 0) r = tmp[0] + tmp[1] + tmp[2] + tmp[3];
  return r;                              // valid on tid 0 only
}

// ---------------- VbT[c][d] = bf16( U[d][c] / sigma[d] ), rows c>=129 zero ----------------
__global__ __launch_bounds__(256) void k_prep(const float* __restrict__ theta,
                                              unsigned short* __restrict__ VbT) {
  int c = blockIdx.x;                    // 0..143
  const float* sg = theta + (size_t)D * K + D;
  float al = (c < K) ? theta[(size_t)D * K + 2 * D + c] : 0.0f;
  for (int d = threadIdx.x; d < D; d += 256) {
    float v;
    if (c < K)       v = theta[(size_t)d * K + c] * al / sg[d];
    else if (c == K) v = 1.0e-3f / sg[d];
    else             v = 0.0f;
    VbT[(size_t)c * D + d] = f2bf(v);
  }
}

// ---------------- column stats of x (fp32 exact; runs after gemm -> L3-hot) ----------------
__global__ __launch_bounds__(256) void k_colstats(const float* __restrict__ x,
                                                  float* __restrict__ colsum,
                                                  float* __restrict__ colsumsq) {
  int d4 = blockIdx.x * 256 + threadIdx.x;       // float4 column index
  int i0 = blockIdx.y * 64;
  float4 s1 = {0, 0, 0, 0}, s2 = {0, 0, 0, 0};
  for (int i = i0; i < i0 + 64; ++i) {
    float4 v = *reinterpret_cast<const float4*>(&x[(size_t)i * D + d4 * 4]);
    s1.x += v.x; s1.y += v.y; s1.z += v.z; s1.w += v.w;
    s2.x += v.x * v.x; s2.y += v.y * v.y; s2.z += v.z * v.z; s2.w += v.w * v.w;
  }
  atomicAdd(&colsum[d4 * 4 + 0], s1.x); atomicAdd(&colsum[d4 * 4 + 1], s1.y);
  atomicAdd(&colsum[d4 * 4 + 2], s1.z); atomicAdd(&colsum[d4 * 4 + 3], s1.w);
  atomicAdd(&colsumsq[d4 * 4 + 0], s2.x); atomicAdd(&colsumsq[d4 * 4 + 1], s2.y);
  atomicAdd(&colsumsq[d4 * 4 + 2], s2.z); atomicAdd(&colsumsq[d4 * 4 + 3], s2.w);
}

// ---------------- M = I + sum_d sigma_d VbT[j][d] VbT[k][d] ----------------
__global__ __launch_bounds__(256) void k_M(const float* __restrict__ theta,
                                           const unsigned short* __restrict__ VbT,
                                           float* __restrict__ M) {
  int j = blockIdx.x, kk2 = blockIdx.y;
  if (kk2 < j) return;                   // symmetry
  const float* sg = theta + (size_t)D * K + D;
  float acc = 0.0f;
  for (int d0 = threadIdx.x * 8; d0 < D; d0 += 2048) {
    uint4 ua = *reinterpret_cast<const uint4*>(&VbT[(size_t)j * D + d0]);
    uint4 ub = *reinterpret_cast<const uint4*>(&VbT[(size_t)kk2 * D + d0]);
    float4 s0 = *reinterpret_cast<const float4*>(&sg[d0]);
    float4 s1 = *reinterpret_cast<const float4*>(&sg[d0 + 4]);
    acc += s0.x * blo(ua.x) * blo(ub.x) + s0.y * bhi(ua.x) * bhi(ub.x)
         + s0.z * blo(ua.y) * blo(ub.y) + s0.w * bhi(ua.y) * bhi(ub.y)
         + s1.x * blo(ua.z) * blo(ub.z) + s1.y * bhi(ua.z) * bhi(ub.z)
         + s1.z * blo(ua.w) * blo(ub.w) + s1.w * bhi(ua.w) * bhi(ub.w);
  }
  float r = blockReduceSum256(acc);
  if (threadIdx.x == 0) {
    float m = r + (j == kk2 ? 1.0f : 0.0f);
    M[j * MS + kk2] = m;
    M[kk2 * MS + j] = m;
  }
}

// ---------------- fused: tvec (b<KP), mvec (KP<=b<2KP), scalars (b==2KP) ----------------
__global__ __launch_bounds__(256) void k_small(const float* __restrict__ theta,
                                               const unsigned short* __restrict__ VbT,
                                               const float* __restrict__ colsum,
                                               const float* __restrict__ colsumsq,
                                               float* __restrict__ tvec,
                                               float* __restrict__ mvec,
                                               float* __restrict__ scalars) {
  int b = blockIdx.x;
  if (b < 2 * KP) {
    int c = (b >= KP) ? b - KP : b;
    const float* src = (b >= KP) ? (theta + (size_t)D * K) : colsum;
    float a = 0.0f;
    for (int d = threadIdx.x; d < D; d += 256) a += bf2f(VbT[(size_t)c * D + d]) * src[d];
    float r = blockReduceSum256(a);
    if (threadIdx.x == 0) { if (b < KP) tvec[c] = r; else mvec[c] = r; }
  } else {
    const float* mu = theta + (size_t)D * K;
    const float* sg = theta + (size_t)D * K + D;
    float a = 0.0f, bb = 0.0f;
    for (int d = threadIdx.x; d < D; d += 256) {
      float s = sg[d];
      float m = mu[d];
      a += logf(s);
      bb += (colsumsq[d] - 2.0f * m * colsum[d] + (float)NROWS * m * m) / s;
    }
    float ra = blockReduceSum256(a);
    float rb = blockReduceSum256(bb);
    if (threadIdx.x == 0) { scalars[0] = ra; scalars[1] = rb; }
  }
}

// ---------------- Yb = bf16( X * V )  via MFMA 16x16x32 ----------------
#define GBM 32
#define GBK 128
#define NSTEP (D / GBK)     // 32
#define XSS 136             // LDS row stride in shorts

__global__ __launch_bounds__(512) void k_gemm(const float* __restrict__ x,
                                              const unsigned short* __restrict__ VbT,
                                              unsigned short* __restrict__ Yb) {
  __shared__ unsigned short Xs[GBM][XSS];   // bf16 X tile
  __shared__ unsigned short Vs[NC][XSS];    // bf16 V^T tile
  int tid = threadIdx.x;
  int row0 = blockIdx.x * GBM;
  int wid = tid >> 6, lane = tid & 63;
  int lr = lane & 15, lk = (lane >> 4) * 8;
  int rt = wid & 1;                         // row tile (16 rows)
  int cg = wid >> 1;                        // col group
  int ct0 = (cg == 0) ? 0 : (cg * 2 + 1);   // col tiles: {0,1,2},{3,4},{5,6},{7,8}
  int nct = (cg == 0) ? 3 : 2;

  int sxr = tid >> 4;                       // X: row 0..31
  int sxk = (tid & 15) * 8;                 // X: k-octet
  int vrb = tid >> 4;                       // V: base row (+32 per j)
  int vk  = (tid & 15) * 8;

  float4 xr0, xr1;
  uint4 vr0, vr1, vr2, vr3, vr4;

  {
    const float* xb = &x[(size_t)(row0 + sxr) * D + sxk];
    xr0 = *reinterpret_cast<const float4*>(xb);
    xr1 = *reinterpret_cast<const float4*>(xb + 4);
    const unsigned short* vb = &VbT[(size_t)vrb * D + vk];
    vr0 = *reinterpret_cast<const uint4*>(vb);
    vr1 = *reinterpret_cast<const uint4*>(vb + (size_t)32 * D);
    vr2 = *reinterpret_cast<const uint4*>(vb + (size_t)64 * D);
    vr3 = *reinterpret_cast<const uint4*>(vb + (size_t)96 * D);
    if (tid < 256) vr4 = *reinterpret_cast<const uint4*>(vb + (size_t)128 * D);
  }

  f32x4 acc0 = {0, 0, 0, 0}, acc1 = {0, 0, 0, 0}, acc2 = {0, 0, 0, 0};

  for (int s = 0; s < NSTEP; ++s) {
    {
      uint4 w;
      w.x = (unsigned)f2bf(xr0.x) | ((unsigned)f2bf(xr0.y) << 16);
      w.y = (unsigned)f2bf(xr0.z) | ((unsigned)f2bf(xr0.w) << 16);
      w.z = (unsigned)f2bf(xr1.x) | ((unsigned)f2bf(xr1.y) << 16);
      w.w = (unsigned)f2bf(xr1.z) | ((unsigned)f2bf(xr1.w) << 16);
      *reinterpret_cast<uint4*>(&Xs[sxr][sxk]) = w;
      unsigned short* vd = &Vs[vrb][vk];
      *reinterpret_cast<uint4*>(vd) = vr0;
      *reinterpret_cast<uint4*>(vd + 32 * XSS) = vr1;
      *reinterpret_cast<uint4*>(vd + 64 * XSS) = vr2;
      *reinterpret_cast<uint4*>(vd + 96 * XSS) = vr3;
      if (tid < 256) *reinterpret_cast<uint4*>(vd + 128 * XSS) = vr4;
    }
    __syncthreads();
    if (s + 1 < NSTEP) {
      const float* xb = &x[(size_t)(row0 + sxr) * D + (s + 1) * GBK + sxk];
      xr0 = *reinterpret_cast<const float4*>(xb);
      xr1 = *reinterpret_cast<const float4*>(xb + 4);
      const unsigned short* vb = &VbT[(size_t)vrb * D + (s + 1) * GBK + vk];
      vr0 = *reinterpret_cast<const uint4*>(vb);
      vr1 = *reinterpret_cast<const uint4*>(vb + (size_t)32 * D);
      vr2 = *reinterpret_cast<const uint4*>(vb + (size_t)64 * D);
      vr3 = *reinterpret_cast<const uint4*>(vb + (size_t)96 * D);
      if (tid < 256) vr4 = *reinterpret_cast<const uint4*>(vb + (size_t)128 * D);
    }
    #pragma unroll
    for (int ks = 0; ks < 4; ++ks) {
      bh8 a = *reinterpret_cast<const bh8*>(&Xs[rt * 16 + lr][ks * 32 + lk]);
      bh8 b0 = *reinterpret_cast<const bh8*>(&Vs[ct0 * 16 + lr][ks * 32 + lk]);
      acc0 = __builtin_amdgcn_mfma_f32_16x16x32_bf16(a, b0, acc0, 0, 0, 0);
      bh8 b1 = *reinterpret_cast<const bh8*>(&Vs[(ct0 + 1) * 16 + lr][ks * 32 + lk]);
      acc1 = __builtin_amdgcn_mfma_f32_16x16x32_bf16(a, b1, acc1, 0, 0, 0);
      if (nct == 3) {
        bh8 b2 = *reinterpret_cast<const bh8*>(&Vs[(ct0 + 2) * 16 + lr][ks * 32 + lk]);
        acc2 = __builtin_amdgcn_mfma_f32_16x16x32_bf16(a, b2, acc2, 0, 0, 0);
      }
    }
    __syncthreads();
  }

  int rw = row0 + rt * 16 + ((lane >> 4) << 2);
  #pragma unroll
  for (int g = 0; g < 4; ++g)
    Yb[(size_t)(rw + g) * NC + ct0 * 16 + lr] = f2bf(acc0[g]);
  #pragma unroll
  for (int g = 0; g < 4; ++g)
    Yb[(size_t)(rw + g) * NC + (ct0 + 1) * 16 + lr] = f2bf(acc1[g]);
  if (nct == 3) {
    #pragma unroll
    for (int g = 0; g < 4; ++g)
      Yb[(size_t)(rw + g) * NC + (ct0 + 2) * 16 + lr] = f2bf(acc2[g]);
  }
}

// ---------------- Q += Yb^T Yb  (bf16 in, symmetry, row-split atomics) ----------------
#define SYRK_ZSPLIT 4
__global__ __launch_bounds__(256) void k_syrk(const unsigned short* __restrict__ Yb,
                                              float* __restrict__ Q) {
  int bj = blockIdx.x * 16, bk = blockIdx.y * 16;
  if (bk < bj) return;                   // symmetry
  __shared__ float Ya[64][17];
  __shared__ float Yc[64][17];
  int i0base = blockIdx.z * (NROWS / SYRK_ZSPLIT);
  int tid = threadIdx.x;
  int tj = tid & 15, tk = tid >> 4;
  int lr = tid >> 2, lc = (tid & 3) * 4;
  float acc = 0.0f;
  for (int i0 = i0base; i0 < i0base + NROWS / SYRK_ZSPLIT; i0 += 64) {
    ushort4 va = *reinterpret_cast<const ushort4*>(&Yb[(size_t)(i0 + lr) * NC + bj + lc]);
    ushort4 vc = *reinterpret_cast<const ushort4*>(&Yb[(size_t)(i0 + lr) * NC + bk + lc]);
    Ya[lr][lc + 0] = bf2f(va.x); Ya[lr][lc + 1] = bf2f(va.y);
    Ya[lr][lc + 2] = bf2f(va.z); Ya[lr][lc + 3] = bf2f(va.w);
    Yc[lr][lc + 0] = bf2f(vc.x); Yc[lr][lc + 1] = bf2f(vc.y);
    Yc[lr][lc + 2] = bf2f(vc.z); Yc[lr][lc + 3] = bf2f(vc.w);
    __syncthreads();
    #pragma unroll
    for (int ii = 0; ii < 64; ++ii) acc += Ya[ii][tj] * Yc[ii][tk];
    __syncthreads();
  }
  atomicAdd(&Q[(bj + tj) * QS + bk + tk], acc);
  if (bj != bk) atomicAdd(&Q[(bk + tk) * QS + bj + tj], acc);
}

// ---------------- final: blocked Cholesky (scalar-redundant diag+inverse) + GEMV solves ----------------
__global__ __launch_bounds__(512) void k_final(const float* __restrict__ Mg,
                                               const float* __restrict__ Qg,
                                               const float* __restrict__ tvec,
                                               const float* __restrict__ mvec,
                                               const float* __restrict__ scalars,
                                               const int* __restrict__ fds,
                                               float* __restrict__ out) {
  __shared__ float A[NP][NP];            // M (identity-padded) -> L panels (below diag)
  __shared__ float Wm[NP][NP];           // S -> M^-1 S
  __shared__ float Gall[NPAN][NB][NB];   // per-panel L_pp^{-1} (lower; upper garbage-free zeros)
  __shared__ float tl[NP], ml[NP];
  __shared__ float redA[8], redB[8];
  int tid = threadIdx.x;

  if (tid < NP) {
    tl[tid] = (tid < KP) ? tvec[tid] : 0.0f;
    ml[tid] = (tid < KP) ? mvec[tid] : 0.0f;
  }
  for (int idx = tid; idx < NP * NP; idx += 512) {
    int r = idx / NP, c = idx - r * NP;
    A[r][c] = (r < KP && c < KP) ? Mg[r * MS + c] : (r == c ? 1.0f : 0.0f);
  }
  __syncthreads();
  for (int idx = tid; idx < NP * NP; idx += 512) {
    int r = idx / NP, c = idx - r * NP;
    float s = 0.0f;
    if (r < KP && c < KP)
      s = Qg[r * QS + c] - tl[r] * ml[c] - ml[r] * tl[c] + (float)NROWS * ml[r] * ml[c];
    Wm[r][c] = s;
  }
  __syncthreads();

  // ======== blocked Cholesky ========
  for (int p = 0; p < NPAN; ++p) {
    int j0 = p * NB, j1 = j0 + NB;
    // (1) 12x12 diag Cholesky + inverse, scalar-redundant on wave 0 (no shfl, no chains
    //     beyond sqrt/rcp; all indices static -> registers, rule #20)
    if (tid < 64) {
      float T[NB][NB];                   // lower triangle only ever touched
      #pragma unroll
      for (int r = 0; r < NB; ++r)
        #pragma unroll
        for (int c = 0; c <= r; ++c)
          T[r][c] = A[j0 + r][j0 + c];
      float dinv[NB];
      #pragma unroll
      for (int jj = 0; jj < NB; ++jj) {
        float dv = sqrtf(T[jj][jj]);
        float iv = 1.0f / dv;
        dinv[jj] = iv;
        T[jj][jj] = dv;
        #pragma unroll
        for (int r = jj + 1; r < NB; ++r) T[r][jj] *= iv;
        #pragma unroll
        for (int cc = jj + 1; cc < NB; ++cc)
          #pragma unroll
          for (int r = cc; r < NB; ++r)
            T[r][cc] -= T[r][jj] * T[cc][jj];
      }
      // in-place inverse, row by row: after row r is transformed, L-row r is dead
      #pragma unroll
      for (int r = 0; r < NB; ++r) {
        float tmp[NB];
        #pragma unroll
        for (int c = 0; c < r; ++c) {
          float s = 0.0f;
          #pragma unroll
          for (int k = c; k < r; ++k) s += T[r][k] * T[k][c];   // T[k][c] already = G
          tmp[c] = -s * dinv[r];
        }
        #pragma unroll
        for (int c = 0; c < r; ++c) T[r][c] = tmp[c];
        T[r][r] = dinv[r];
      }
      // lane 0 writes G (upper zeros) as float4s
      if (tid == 0) {
        #pragma unroll
        for (int r = 0; r < NB; ++r) {
          float4 g0 = {T[r][0], (r >= 1 ? T[r][1] : 0.f), (r >= 2 ? T[r][2] : 0.f), (r >= 3 ? T[r][3] : 0.f)};
          float4 g1 = {(r >= 4 ? T[r][4] : 0.f), (r >= 5 ? T[r][5] : 0.f), (r >= 6 ? T[r][6] : 0.f), (r >= 7 ? T[r][7] : 0.f)};
          float4 g2 = {(r >= 8 ? T[r][8] : 0.f), (r >= 9 ? T[r][9] : 0.f), (r >= 10 ? T[r][10] : 0.f), T[r][11]};
          if (r < 1) g0.x = T[0][0];     // keep static: r==0 handled by init above
          *reinterpret_cast<float4*>(&Gall[p][r][0]) = g0;
          *reinterpret_cast<float4*>(&Gall[p][r][4]) = g1;
          *reinterpret_cast<float4*>(&Gall[p][r][8]) = g2;
        }
      }
    }
    __syncthreads();
    // (2) panel solve rows j1..NP: row_new = row_old * G^T   (independent FMAs)
    int nbrows = NP - j1;
    if (tid < nbrows) {
      int r = j1 + tid;
      float* arow = &A[r][j0];
      float4 q0 = *reinterpret_cast<const float4*>(arow);
      float4 q1 = *reinterpret_cast<const float4*>(arow + 4);
      float4 q2 = *reinterpret_cast<const float4*>(arow + 8);
      float ro[NB] = {q0.x, q0.y, q0.z, q0.w, q1.x, q1.y, q1.z, q1.w,
                      q2.x, q2.y, q2.z, q2.w};
      float rn[NB];
      #pragma unroll
      for (int cc = 0; cc < NB; ++cc) {
        float s = 0.0f;
        #pragma unroll
        for (int k = 0; k <= cc; ++k) s += ro[k] * Gall[p][cc][k];
        rn[cc] = s;
      }
      float4 w0 = {rn[0], rn[1], rn[2], rn[3]};
      float4 w1 = {rn[4], rn[5], rn[6], rn[7]};
      float4 w2 = {rn[8], rn[9], rn[10], rn[11]};
      *reinterpret_cast<float4*>(arow) = w0;
      *reinterpret_cast<float4*>(arow + 4) = w1;
      *reinterpret_cast<float4*>(arow + 8) = w2;
    }
    __syncthreads();
    // (3) trailing rank-12 update, lower blocks only, 4x4 tasks
    int nt4 = nbrows / 4;
    for (int t = tid; t < nt4 * nt4; t += 512) {
      int r4 = t / nt4, c4 = t - r4 * nt4;
      if (c4 > r4) continue;
      int r = j1 + r4 * 4, c = j1 + c4 * 4;
      float4 a0 = *reinterpret_cast<float4*>(&A[r + 0][c]);
      float4 a1 = *reinterpret_cast<float4*>(&A[r + 1][c]);
      float4 a2 = *reinterpret_cast<float4*>(&A[r + 2][c]);
      float4 a3 = *reinterpret_cast<float4*>(&A[r + 3][c]);
      #pragma unroll
      for (int k = 0; k < NB; ++k) {
        float pc0 = A[c + 0][j0 + k], pc1 = A[c + 1][j0 + k];
        float pc2 = A[c + 2][j0 + k], pc3 = A[c + 3][j0 + k];
        float pr0 = A[r + 0][j0 + k], pr1 = A[r + 1][j0 + k];
        float pr2 = A[r + 2][j0 + k], pr3 = A[r + 3][j0 + k];
        a0.x -= pr0 * pc0; a0.y -= pr0 * pc1; a0.z -= pr0 * pc2; a0.w -= pr0 * pc3;
        a1.x -= pr1 * pc0; a1.y -= pr1 * pc1; a1.z -= pr1 * pc2; a1.w -= pr1 * pc3;
        a2.x -= pr2 * pc0; a2.y -= pr2 * pc1; a2.z -= pr2 * pc2; a2.w -= pr2 * pc3;
        a3.x -= pr3 * pc0; a3.y -= pr3 * pc1; a3.z -= pr3 * pc2; a3.w -= pr3 * pc3;
      }
      *reinterpret_cast<float4*>(&A[r + 0][c]) = a0;
      *reinterpret_cast<float4*>(&A[r + 1][c]) = a1;
      *reinterpret_cast<float4*>(&A[r + 2][c]) = a2;
      *reinterpret_cast<float4*>(&A[r + 3][c]) = a3;
    }
    __syncthreads();
  }

  // ======== forward solve: L W = S  (diag step = GEMV with G) ========
  for (int p = 0; p < NPAN; ++p) {
    int j0 = p * NB, j1 = j0 + NB;
    if (tid < NP) {
      int c = tid;
      float w[NB], wn[NB];
      #pragma unroll
      for (int k = 0; k < NB; ++k) w[k] = Wm[j0 + k][c];
      #pragma unroll
      for (int kk = 0; kk < NB; ++kk) {
        float s = 0.0f;
        #pragma unroll
        for (int k = 0; k <= kk; ++k) s += Gall[p][kk][k] * w[k];
        wn[kk] = s;
      }
      #pragma unroll
      for (int k = 0; k < NB; ++k) Wm[j0 + k][c] = wn[k];
    }
    __syncthreads();
    int nbrows = NP - j1;
    int nr4 = nbrows / 4, nc4 = NP / 4;
    for (int t = tid; t < nr4 * nc4; t += 512) {
      int r4 = t / nc4, c4 = t - r4 * nc4;
      int r = j1 + r4 * 4, c = c4 * 4;
      float4 a0 = *reinterpret_cast<float4*>(&Wm[r + 0][c]);
      float4 a1 = *reinterpret_cast<float4*>(&Wm[r + 1][c]);
      float4 a2 = *reinterpret_cast<float4*>(&Wm[r + 2][c]);
      float4 a3 = *reinterpret_cast<float4*>(&Wm[r + 3][c]);
      #pragma unroll
      for (int k = 0; k < NB; ++k) {
        float l0 = A[r + 0][j0 + k], l1 = A[r + 1][j0 + k];
        float l2 = A[r + 2][j0 + k], l3 = A[r + 3][j0 + k];
        float4 wr = *reinterpret_cast<const float4*>(&Wm[j0 + k][c]);
        a0.x -= l0 * wr.x; a0.y -= l0 * wr.y; a0.z -= l0 * wr.z; a0.w -= l0 * wr.w;
        a1.x -= l1 * wr.x; a1.y -= l1 * wr.y; a1.z -= l1 * wr.z; a1.w -= l1 * wr.w;
        a2.x -= l2 * wr.x; a2.y -= l2 * wr.y; a2.z -= l2 * wr.z; a2.w -= l2 * wr.w;
        a3.x -= l3 * wr.x; a3.y -= l3 * wr.y; a3.z -= l3 * wr.z; a3.w -= l3 * wr.w;
      }
      *reinterpret_cast<float4*>(&Wm[r + 0][c]) = a0;
      *reinterpret_cast<float4*>(&Wm[r + 1][c]) = a1;
      *reinterpret_cast<float4*>(&Wm[r + 2][c]) = a2;
      *reinterpret_cast<float4*>(&Wm[r + 3][c]) = a3;
    }
    __syncthreads();
  }

  // ======== backward solve: L^T U = W  (diag step = GEMV with G^T) ========
  for (int p = NPAN - 1; p >= 0; --p) {
    int j0 = p * NB;
    if (tid < NP) {
      int c = tid;
      float w[NB], wn[NB];
      #pragma unroll
      for (int k = 0; k < NB; ++k) w[k] = Wm[j0 + k][c];
      #pragma unroll
      for (int kk = 0; kk < NB; ++kk) {
        float s = 0.0f;
        #pragma unroll
        for (int k = kk; k < NB; ++k) s += Gall[p][k][kk] * w[k];
        wn[kk] = s;
      }
      #pragma unroll
      for (int k = 0; k < NB; ++k) Wm[j0 + k][c] = wn[k];
    }
    __syncthreads();
    int nr4 = j0 / 4, nc4 = NP / 4;
    for (int t = tid; t < nr4 * nc4; t += 512) {
      int r4 = t / nc4, c4 = t - r4 * nc4;
      int r = r4 * 4, c = c4 * 4;
      float4 a0 = *reinterpret_cast<float4*>(&Wm[r + 0][c]);
      float4 a1 = *reinterpret_cast<float4*>(&Wm[r + 1][c]);
      float4 a2 = *reinterpret_cast<float4*>(&Wm[r + 2][c]);
      float4 a3 = *reinterpret_cast<float4*>(&Wm[r + 3][c]);
      #pragma unroll
      for (int k = 0; k < NB; ++k) {
        float l0 = A[j0 + k][r + 0], l1 = A[j0 + k][r + 1];
        float l2 = A[j0 + k][r + 2], l3 = A[j0 + k][r + 3];
        float4 wr = *reinterpret_cast<const float4*>(&Wm[j0 + k][c]);
        a0.x -= l0 * wr.x; a0.y -= l0 * wr.y; a0.z -= l0 * wr.z; a0.w -= l0 * wr.w;
        a1.x -= l1 * wr.x; a1.y -= l1 * wr.y; a1.z -= l1 * wr.z; a1.w -= l1 * wr.w;
        a2.x -= l2 * wr.x; a2.y -= l2 * wr.y; a2.z -= l2 * wr.z; a2.w -= l2 * wr.w;
        a3.x -= l3 * wr.x; a3.y -= l3 * wr.y; a3.z -= l3 * wr.z; a3.w -= l3 * wr.w;
      }
      *reinterpret_cast<float4*>(&Wm[r + 0][c]) = a0;
      *reinterpret_cast<float4*>(&Wm[r + 1][c]) = a1;
      *reinterpret_cast<float4*>(&Wm[r + 2][c]) = a2;
      *reinterpret_cast<float4*>(&Wm[r + 3][c]) = a3;
    }
    __syncthreads();
  }

  // ======== trace + logdet (from diag(G) = 1/diag(L)) + combine ========
  float dv = (tid < KP) ? Wm[tid][tid] : 0.0f;
  float lg = 0.0f;
  if (tid < NP) {
    int pp = tid / NB, rr = tid - pp * NB;
    lg = logf(Gall[pp][rr][rr]);         // = -log(diag L)
  }
  float v1 = dv, v2 = lg;
  #pragma unroll
  for (int off = 32; off > 0; off >>= 1) {
    v1 += __shfl_down(v1, off, 64);
    v2 += __shfl_down(v2, off, 64);
  }
  if ((tid & 63) == 0) { redA[tid >> 6] = v1; redB[tid >> 6] = v2; }
  __syncthreads();
  if (tid == 0) {
    float tr = 0.0f, sgl = 0.0f;
    #pragma unroll
    for (int i = 0; i < 8; ++i) { tr += redA[i]; sgl += redB[i]; }
    float logdetM = -2.0f * sgl;
    double sumlog = (double)scalars[0];
    double term1  = (double)scalars[1];
    double total = (double)NROWS * (double)D * LOG2PI
                 + (double)NROWS * (sumlog + (double)logdetM)
                 + term1 - (double)tr;
    double scale = (double)fds[0] / (double)NROWS;
    out[0] = (float)(scale * (-0.5) * total);
  }
}

// ---------------- launch ----------------
extern "C" void kernel_launch(void* const* d_in, const int* in_sizes, int n_in,
                              void* d_out, int out_size, void* d_ws, size_t ws_size,
                              hipStream_t stream) {
  const float* x     = (const float*)d_in[0];
  const float* theta = (const float*)d_in[1];
  const int*   fds   = (const int*)d_in[2];
  float* out = (float*)d_out;
  char* ws = (char*)d_ws;

  unsigned short* Yb  = (unsigned short*)ws;                       // 8192*144*2 = 2359296
  unsigned short* VbT = (unsigned short*)(ws + 2359296);           // 144*4096*2 = 1179648
  float* Q        = (float*)(ws + 2359296 + 1179648);              // QS*QS*4 = 82944
  float* colsum   = (float*)(ws + 2359296 + 1179648 + 82944);      // D*4
  float* colsumsq = colsum + D;                                    // D*4
  float* M        = colsumsq + D;                                  // KP*MS*4
  float* tvec     = M + KP * MS;
  float* mvec     = tvec + MS;
  float* scalars  = mvec + MS;

  // zero atomic accumulators: Q + colsum + colsumsq (contiguous)
  hipMemsetAsync(Q, 0, (size_t)(QS * QS + 2 * D) * sizeof(float), stream);

  k_prep     <<<dim3(NC), 256, 0, stream>>>(theta, VbT);
  k_gemm     <<<dim3(NROWS / GBM), 512, 0, stream>>>(x, VbT, Yb);
  k_syrk     <<<dim3(QS / 16, QS / 16, SYRK_ZSPLIT), 256, 0, stream>>>(Yb, Q);
  k_M        <<<dim3(KP, KP), 256, 0, stream>>>(theta, VbT, M);
  k_colstats <<<dim3(D / 4 / 256, 128), 256, 0, stream>>>(x, colsum, colsumsq);
  k_small    <<<dim3(2 * KP + 1), 256, 0, stream>>>(theta, VbT, colsum, colsumsq,
                                                    tvec, mvec, scalars);
  k_final    <<<dim3(1), 512, 0, stream>>>(M, Q, tvec, mvec, scalars, fds, out);
}